// Round 10
// baseline (519.258 us; speedup 1.0000x reference)
//
#include <hip/hip_runtime.h>
#include <math.h>

#define ROI 84
#define WIN 12
#define HID 128
#define BATCH 64
#define SEQ (ROI * WIN)              // 1008
#define NNODE (BATCH * SEQ)          // 64512
#define NEDGE (NNODE * 16)           // 1032192
#define MAXDEG 64

typedef __attribute__((ext_vector_type(8))) __bf16 bf16x8;
typedef __attribute__((ext_vector_type(4))) float f32x4;
typedef __attribute__((ext_vector_type(8))) unsigned short u16x8;

__device__ inline unsigned short f2bf(float x) {
    union { float f; unsigned u; } v; v.f = x;
    unsigned r = v.u + 0x7fff + ((v.u >> 16) & 1);   // RNE
    return (unsigned short)(r >> 16);
}

__device__ inline float bf2f(unsigned short u) {
    union { unsigned u; float f; } v; v.u = (unsigned)u << 16;
    return v.f;
}

// ---------------- CSR build ----------------

__global__ void k_scatter(const int* __restrict__ ei, int* __restrict__ fill,
                          int* __restrict__ csr) {
    int e = blockIdx.x * 256 + threadIdx.x;
    if (e >= NEDGE) return;
    bool is64 = true;
#pragma unroll
    for (int k = 0; k < 8; ++k) is64 = is64 && (ei[2 * k + 1] == 0);
    int s, d;
    if (is64) { s = ei[2 * e]; d = ei[2 * (NEDGE + e)]; }
    else      { s = ei[e];     d = ei[NEDGE + e]; }
    if (s < 0 || s >= NNODE || d < 0 || d >= NNODE) return;
    int pos = atomicAdd(&fill[d], 1);
    if (pos < MAXDEG) csr[d * MAXDEG + pos] = s;
}

// ---------------- W -> MFMA B-fragment layout (bf16), both weights ----------------
// Wt[((kb*4+ko)*128+col)*8+j] = W[kb*32+ko*8+j][col]  (0 beyond KACT)

__global__ void k_prepW(const float* __restrict__ W1, const float* __restrict__ W2,
                        unsigned short* __restrict__ Wt1, unsigned short* __restrict__ Wt2) {
    int g = blockIdx.x * 256 + threadIdx.x;
    if (g < 1536) {                                  // Wt1: KB=3, KACT=84
        int col = g & 127, kq = g >> 7;
        u16x8 o;
#pragma unroll
        for (int j = 0; j < 8; ++j) {
            int k = kq * 8 + j;
            o[j] = (k < 84) ? f2bf(W1[(size_t)k * 128 + col]) : (unsigned short)0;
        }
        *(u16x8*)&Wt1[(size_t)g * 8] = o;
    } else if (g < 1536 + 2048) {                    // Wt2: KB=4, KACT=128
        int g2 = g - 1536;
        int col = g2 & 127, kq = g2 >> 7;
        u16x8 o;
#pragma unroll
        for (int j = 0; j < 8; ++j)
            o[j] = f2bf(W2[(size_t)(kq * 8 + j) * 128 + col]);
        *(u16x8*)&Wt2[(size_t)g2 * 8] = o;
    }
}

// ---------------- fused GIN layer 1: gather(x) -> bf16 LDS -> MFMA -> t1b ----------
// 504 blocks x 128 rows. LDS A-tile 128x96 bf16 (24KB), XOR-swizzled.

__global__ __launch_bounds__(256)
void k_gin1(const float4* __restrict__ x4, const int* __restrict__ fill,
            const int* __restrict__ csr, const unsigned short* __restrict__ Wt,
            const float* __restrict__ bias, unsigned short* __restrict__ t1b) {
    __shared__ unsigned short As[128 * 96];
    const int t = threadIdx.x;
    const int row0 = blockIdx.x * 128;

    // stage: 128 rows x 12 chunks of 8 cols; gather + sum in fp32, store bf16
    for (int u = t; u < 128 * 12; u += 256) {
        int row = u / 12, f8 = u - row * 12;
        int n = row0 + row;
        int c0 = f8 * 8;
        bool ok0 = (c0 < 84), ok1 = (c0 + 4 < 84);
        float s[8];
#pragma unroll
        for (int e = 0; e < 8; ++e) s[e] = 0.f;
        if (ok0) {
            int deg = fill[n];
            if (deg > MAXDEG) deg = MAXDEG;
            const int* lst = csr + n * MAXDEG;
            float4 a = x4[(size_t)n * 21 + f8 * 2];
            s[0] = a.x; s[1] = a.y; s[2] = a.z; s[3] = a.w;
            if (ok1) {
                float4 bq = x4[(size_t)n * 21 + f8 * 2 + 1];
                s[4] = bq.x; s[5] = bq.y; s[6] = bq.z; s[7] = bq.w;
            }
            for (int j = 0; j < deg; ++j) {
                int nb = lst[j];
                float4 a2 = x4[(size_t)nb * 21 + f8 * 2];
                s[0] += a2.x; s[1] += a2.y; s[2] += a2.z; s[3] += a2.w;
                if (ok1) {
                    float4 b2 = x4[(size_t)nb * 21 + f8 * 2 + 1];
                    s[4] += b2.x; s[5] += b2.y; s[6] += b2.z; s[7] += b2.w;
                }
            }
        }
        u16x8 o;
#pragma unroll
        for (int e = 0; e < 8; ++e) o[e] = f2bf(s[e]);
        *(u16x8*)((char*)As + ((row * 192 + f8 * 16) ^ ((row & 7) << 4))) = o;
    }
    __syncthreads();

    // MFMA: KB=3
    const int lane = t & 63;
    const int w = t >> 6;
    const int r = lane & 15;
    const int h = lane >> 4;
    f32x4 acc0[8], acc1[8];
#pragma unroll
    for (int cb = 0; cb < 8; ++cb) {
        acc0[cb] = (f32x4){0.f, 0.f, 0.f, 0.f};
        acc1[cb] = (f32x4){0.f, 0.f, 0.f, 0.f};
    }
#pragma unroll
    for (int kb = 0; kb < 3; ++kb) {
        const int ra = w * 32 + r;
        const int rb = w * 32 + 16 + r;
        bf16x8 pa0 = *(const bf16x8*)((const char*)As +
            ((ra * 192 + kb * 64 + h * 16) ^ ((ra & 7) << 4)));
        bf16x8 pa1 = *(const bf16x8*)((const char*)As +
            ((rb * 192 + kb * 64 + h * 16) ^ ((rb & 7) << 4)));
#pragma unroll
        for (int cb = 0; cb < 8; ++cb) {
            bf16x8 wv = *(const bf16x8*)&Wt[(size_t)((kb * 4 + h) * 128 + cb * 16 + r) * 8];
            acc0[cb] = __builtin_amdgcn_mfma_f32_16x16x32_bf16(pa0, wv, acc0[cb], 0, 0, 0);
            acc1[cb] = __builtin_amdgcn_mfma_f32_16x16x32_bf16(pa1, wv, acc1[cb], 0, 0, 0);
        }
    }
#pragma unroll
    for (int cb = 0; cb < 8; ++cb) {
        int col = cb * 16 + r;
        float bv = bias[col];
#pragma unroll
        for (int i = 0; i < 4; ++i) {
            int g0 = row0 + w * 32 + h * 4 + i;
            int g1 = g0 + 16;
            t1b[(size_t)g0 * 128 + col] = f2bf(acc0[cb][i] + bv);
            t1b[(size_t)g1 * 128 + col] = f2bf(acc1[cb][i] + bv);
        }
    }
}

// ---------------- fused GIN layer 2: gather(t1b) -> LDS -> MFMA (+pe) -> qbf ------
// LDS A-tile 128x128 bf16 (32KB), XOR-swizzled.

__global__ __launch_bounds__(256)
void k_gin2(const unsigned short* __restrict__ t1b, const int* __restrict__ fill,
            const int* __restrict__ csr, const unsigned short* __restrict__ Wt,
            const float* __restrict__ bias, const float* __restrict__ pe,
            unsigned short* __restrict__ qbf) {
    __shared__ unsigned short As[128 * 128];
    const int t = threadIdx.x;
    const int row0 = blockIdx.x * 128;

    for (int u = t; u < 128 * 16; u += 256) {
        int row = u >> 4, f8 = u & 15;
        int n = row0 + row;
        int deg = fill[n];
        if (deg > MAXDEG) deg = MAXDEG;
        const int* lst = csr + n * MAXDEG;
        u16x8 own = *(const u16x8*)&t1b[(size_t)n * 128 + f8 * 8];
        float s[8];
#pragma unroll
        for (int e = 0; e < 8; ++e) s[e] = bf2f(own[e]);
        for (int j = 0; j < deg; ++j) {
            u16x8 v = *(const u16x8*)&t1b[(size_t)lst[j] * 128 + f8 * 8];
#pragma unroll
            for (int e = 0; e < 8; ++e) s[e] += bf2f(v[e]);
        }
        u16x8 o;
#pragma unroll
        for (int e = 0; e < 8; ++e) o[e] = f2bf(s[e]);
        *(u16x8*)((char*)As + ((row * 256 + f8 * 16) ^ ((row & 7) << 4))) = o;
    }
    __syncthreads();

    const int lane = t & 63;
    const int w = t >> 6;
    const int r = lane & 15;
    const int h = lane >> 4;
    f32x4 acc0[8], acc1[8];
#pragma unroll
    for (int cb = 0; cb < 8; ++cb) {
        acc0[cb] = (f32x4){0.f, 0.f, 0.f, 0.f};
        acc1[cb] = (f32x4){0.f, 0.f, 0.f, 0.f};
    }
#pragma unroll
    for (int kb = 0; kb < 4; ++kb) {
        const int ra = w * 32 + r;
        const int rb = w * 32 + 16 + r;
        bf16x8 pa0 = *(const bf16x8*)((const char*)As +
            ((ra * 256 + kb * 64 + h * 16) ^ ((ra & 7) << 4)));
        bf16x8 pa1 = *(const bf16x8*)((const char*)As +
            ((rb * 256 + kb * 64 + h * 16) ^ ((rb & 7) << 4)));
#pragma unroll
        for (int cb = 0; cb < 8; ++cb) {
            bf16x8 wv = *(const bf16x8*)&Wt[(size_t)((kb * 4 + h) * 128 + cb * 16 + r) * 8];
            acc0[cb] = __builtin_amdgcn_mfma_f32_16x16x32_bf16(pa0, wv, acc0[cb], 0, 0, 0);
            acc1[cb] = __builtin_amdgcn_mfma_f32_16x16x32_bf16(pa1, wv, acc1[cb], 0, 0, 0);
        }
    }
#pragma unroll
    for (int cb = 0; cb < 8; ++cb) {
        int col = cb * 16 + r;
        float bv = bias[col];
#pragma unroll
        for (int i = 0; i < 4; ++i) {
            int g0 = row0 + w * 32 + h * 4 + i;
            int g1 = g0 + 16;
            float v0 = acc0[cb][i] + bv + pe[(size_t)(g0 % SEQ) * 128 + col];
            float v1 = acc1[cb][i] + bv + pe[(size_t)(g1 % SEQ) * 128 + col];
            qbf[(size_t)g0 * 128 + col] = f2bf(v0);
            qbf[(size_t)g1 * 128 + col] = f2bf(v1);
        }
    }
}

// ---------------- MFMA flash self-attention (q = k = v) ----------------
// 512 blocks (64 batches x 8 q-tiles of 128 rows), 4 waves; XCD swizzle keeps
// each batch's K/V L2-resident. Register-prefetched staging; defer-rescale THR=8.

struct Stg { u16x8 a0, a1, c0, c1; };

__device__ inline Stg load_stage(const unsigned short* qb, int kt, int t) {
    const int kp = t >> 3;
    const int dseg = (t & 7) * 16;
    const int g0 = kt * 64 + kp * 2;
    const u16x8 zz = {0, 0, 0, 0, 0, 0, 0, 0};
    Stg s; s.a0 = zz; s.a1 = zz; s.c0 = zz; s.c1 = zz;
    if (g0 < SEQ) {
        s.a0 = *(const u16x8*)&qb[(size_t)g0 * 128 + dseg];
        s.a1 = *(const u16x8*)&qb[(size_t)g0 * 128 + dseg + 8];
    }
    if (g0 + 1 < SEQ) {
        s.c0 = *(const u16x8*)&qb[(size_t)(g0 + 1) * 128 + dseg];
        s.c1 = *(const u16x8*)&qb[(size_t)(g0 + 1) * 128 + dseg + 8];
    }
    return s;
}

__device__ inline void write_stage(unsigned short* Ks, unsigned short* Vt,
                                   const Stg& s, int t) {
    const int kp = t >> 3;
    const int dseg = (t & 7) * 16;
    const int k0 = kp * 2, k1 = k0 + 1;
    *(u16x8*)((char*)Ks + ((k0 * 256 + dseg * 2) ^ ((k0 & 7) << 4))) = s.a0;
    *(u16x8*)((char*)Ks + ((k0 * 256 + dseg * 2 + 16) ^ ((k0 & 7) << 4))) = s.a1;
    *(u16x8*)((char*)Ks + ((k1 * 256 + dseg * 2) ^ ((k1 & 7) << 4))) = s.c0;
    *(u16x8*)((char*)Ks + ((k1 * 256 + dseg * 2 + 16) ^ ((k1 & 7) << 4))) = s.c1;
#pragma unroll
    for (int j = 0; j < 16; ++j) {
        int d = dseg + j;
        unsigned short lo = (j < 8) ? s.a0[j] : s.a1[j - 8];
        unsigned short hi = (j < 8) ? s.c0[j] : s.c1[j - 8];
        unsigned val = (unsigned)lo | ((unsigned)hi << 16);
        *(unsigned*)((char*)Vt + ((d * 128 + k0 * 2) ^ ((d & 7) << 4)
                                  ^ (((d >> 4) & 3) << 5))) = val;
    }
}

__global__ __launch_bounds__(256, 2)
void k_flash_mfma(const unsigned short* __restrict__ qbf,
                  unsigned short* __restrict__ ctxb) {
    __shared__ unsigned short Ks[64 * 128];
    __shared__ unsigned short Vt[128 * 64];
    __shared__ unsigned short Pl[4][2][1024];

    const int t = threadIdx.x;
    const int lane = t & 63;
    const int w = t >> 6;
    const int r = lane & 15;
    const int h = lane >> 4;
    const int p = blockIdx.x;
    const int grp = p >> 3;
    const int b = (grp >> 3) * 8 + (p & 7);
    const int qrow0 = (grp & 7) * 128;
    const unsigned short* qb = qbf + (size_t)b * SEQ * HID;

    bf16x8 Qf[2][4];
#pragma unroll
    for (int qa = 0; qa < 2; ++qa) {
        int qrow = qrow0 + w * 32 + qa * 16 + r;
        int qrc = qrow < SEQ ? qrow : SEQ - 1;
#pragma unroll
        for (int ds = 0; ds < 4; ++ds)
            Qf[qa][ds] = *(const bf16x8*)&qb[(size_t)qrc * 128 + ds * 32 + h * 8];
    }

    f32x4 O[2][8];
#pragma unroll
    for (int qa = 0; qa < 2; ++qa)
#pragma unroll
        for (int dt = 0; dt < 8; ++dt) O[qa][dt] = (f32x4){0.f, 0.f, 0.f, 0.f};
    float m_[2][4], l_[2][4];
#pragma unroll
    for (int qa = 0; qa < 2; ++qa)
#pragma unroll
        for (int i = 0; i < 4; ++i) { m_[qa][i] = -1e30f; l_[qa][i] = 0.f; }

    const float scale = 0.08838834764831845f;  // 1/sqrt(128)

    Stg cur = load_stage(qb, 0, t);

    for (int kt = 0; kt < 16; ++kt) {
        __syncthreads();
        write_stage(Ks, Vt, cur, t);
        if (kt < 15) cur = load_stage(qb, kt + 1, t);
        __syncthreads();

        // ---- QK^T ----
        f32x4 S[2][4];
        __builtin_amdgcn_s_setprio(1);
#pragma unroll
        for (int kt4 = 0; kt4 < 4; ++kt4) {
            int key = kt4 * 16 + r;
            f32x4 s0 = (f32x4){0.f, 0.f, 0.f, 0.f};
            f32x4 s1 = (f32x4){0.f, 0.f, 0.f, 0.f};
#pragma unroll
            for (int ds = 0; ds < 4; ++ds) {
                bf16x8 kb = *(const bf16x8*)((const char*)Ks +
                    ((key * 256 + (ds * 32 + h * 8) * 2) ^ ((key & 7) << 4)));
                s0 = __builtin_amdgcn_mfma_f32_16x16x32_bf16(Qf[0][ds], kb, s0, 0, 0, 0);
                s1 = __builtin_amdgcn_mfma_f32_16x16x32_bf16(Qf[1][ds], kb, s1, 0, 0, 0);
            }
            S[0][kt4] = s0; S[1][kt4] = s1;
        }
        __builtin_amdgcn_s_setprio(0);

        // ---- scale + mask + per-row tile max ----
        float pmax[2][4];
#pragma unroll
        for (int qa = 0; qa < 2; ++qa)
#pragma unroll
            for (int i = 0; i < 4; ++i) pmax[qa][i] = -1e30f;
#pragma unroll
        for (int qa = 0; qa < 2; ++qa)
#pragma unroll
            for (int kt4 = 0; kt4 < 4; ++kt4) {
                bool kvalid = (kt * 64 + kt4 * 16 + r) < SEQ;
#pragma unroll
                for (int i = 0; i < 4; ++i) {
                    float v = kvalid ? S[qa][kt4][i] * scale : -1e30f;
                    S[qa][kt4][i] = v;
                    pmax[qa][i] = fmaxf(pmax[qa][i], v);
                }
            }
#pragma unroll
        for (int qa = 0; qa < 2; ++qa)
#pragma unroll
            for (int i = 0; i < 4; ++i) {
                float v = pmax[qa][i];
                v = fmaxf(v, __shfl_xor(v, 1));
                v = fmaxf(v, __shfl_xor(v, 2));
                v = fmaxf(v, __shfl_xor(v, 4));
                v = fmaxf(v, __shfl_xor(v, 8));
                pmax[qa][i] = v;
            }

        // ---- defer-rescale: only update m/rescale when growth > THR ----
        float need = -1e30f;
#pragma unroll
        for (int qa = 0; qa < 2; ++qa)
#pragma unroll
            for (int i = 0; i < 4; ++i)
                need = fmaxf(need, pmax[qa][i] - m_[qa][i]);
        need = fmaxf(need, __shfl_xor(need, 16));
        need = fmaxf(need, __shfl_xor(need, 32));
        if (need > 8.f) {
#pragma unroll
            for (int qa = 0; qa < 2; ++qa)
#pragma unroll
                for (int i = 0; i < 4; ++i) {
                    float mn = fmaxf(m_[qa][i], pmax[qa][i]);
                    float alpha = __expf(m_[qa][i] - mn);
                    m_[qa][i] = mn;
                    l_[qa][i] *= alpha;
#pragma unroll
                    for (int dt = 0; dt < 8; ++dt) O[qa][dt][i] *= alpha;
                }
        }

        // ---- P = exp(S - m), accumulate l, store P to LDS ----
#pragma unroll
        for (int qa = 0; qa < 2; ++qa) {
            char* Pw = (char*)&Pl[w][qa][0];
            float ps[4] = {0.f, 0.f, 0.f, 0.f};
#pragma unroll
            for (int kt4 = 0; kt4 < 4; ++kt4)
#pragma unroll
                for (int i = 0; i < 4; ++i) {
                    float pv = __expf(S[qa][kt4][i] - m_[qa][i]);
                    ps[i] += pv;
                    *(unsigned short*)(Pw + (((h * 4 + i) * 128 + (kt4 * 16 + r) * 2)
                                             ^ (((h * 4 + i) & 7) << 4))) = f2bf(pv);
                }
#pragma unroll
            for (int i = 0; i < 4; ++i) {
                float v = ps[i];
                v += __shfl_xor(v, 1);
                v += __shfl_xor(v, 2);
                v += __shfl_xor(v, 4);
                v += __shfl_xor(v, 8);
                l_[qa][i] += v;
            }
        }

        // ---- PV ----
        __builtin_amdgcn_s_setprio(1);
#pragma unroll
        for (int kstep = 0; kstep < 2; ++kstep) {
            bf16x8 pa0 = *(const bf16x8*)((const char*)&Pl[w][0][0] +
                ((r * 128 + (kstep * 32 + h * 8) * 2) ^ ((r & 7) << 4)));
            bf16x8 pa1 = *(const bf16x8*)((const char*)&Pl[w][1][0] +
                ((r * 128 + (kstep * 32 + h * 8) * 2) ^ ((r & 7) << 4)));
#pragma unroll
            for (int dt = 0; dt < 8; ++dt) {
                int d = dt * 16 + r;
                bf16x8 vb = *(const bf16x8*)((const char*)Vt +
                    ((d * 128 + (kstep * 32 + h * 8) * 2) ^ ((d & 7) << 4)
                     ^ (((d >> 4) & 3) << 5)));
                O[0][dt] = __builtin_amdgcn_mfma_f32_16x16x32_bf16(pa0, vb, O[0][dt], 0, 0, 0);
                O[1][dt] = __builtin_amdgcn_mfma_f32_16x16x32_bf16(pa1, vb, O[1][dt], 0, 0, 0);
            }
        }
        __builtin_amdgcn_s_setprio(0);
    }

    // ---- epilogue: bf16 ctx ----
#pragma unroll
    for (int qa = 0; qa < 2; ++qa)
#pragma unroll
        for (int i = 0; i < 4; ++i) {
            int qq = qrow0 + w * 32 + qa * 16 + h * 4 + i;
            if (qq < SEQ) {
                float inv = 1.f / l_[qa][i];
                size_t base = ((size_t)b * SEQ + qq) * 128 + r;
#pragma unroll
                for (int dt = 0; dt < 8; ++dt)
                    ctxb[base + dt * 16] = f2bf(O[qa][dt][i] * inv);
            }
        }
}

// ---------------- pooling (bf16 inputs) ----------------

__global__ void k_pool(const unsigned short* __restrict__ t1b,
                       const unsigned short* __restrict__ ctxb,
                       float* __restrict__ aggr) {
    int bw = blockIdx.x;
    int b = bw / WIN, w = bw - b * WIN;
    int c = threadIdx.x;
    const unsigned short* p1 = t1b + ((size_t)(b * SEQ + w * ROI)) * HID + c;
    const unsigned short* p2 = ctxb + ((size_t)(b * SEQ + w * ROI)) * HID + c;
    float mx1 = -INFINITY, sm1 = 0.f, mx2 = -INFINITY, sm2 = 0.f;
    for (int r = 0; r < ROI; ++r) {
        float a = bf2f(p1[r * HID]); mx1 = fmaxf(mx1, a); sm1 += a;
        float d = bf2f(p2[r * HID]); mx2 = fmaxf(mx2, d); sm2 += d;
    }
    float* o = aggr + (size_t)b * 6144 + w * 512;
    o[c] = mx1;
    o[128 + c] = sm1 * (1.f / 84.f);
    o[256 + c] = mx2;
    o[384 + c] = sm2 * (1.f / 84.f);
}

// ---------------- fc1 split-K ----------------

#define KSPLIT 48

__global__ __launch_bounds__(256)
void k_fc1_partial(const float* __restrict__ aggr, const float* __restrict__ W,
                   float* __restrict__ part) {
    __shared__ float As[64 * 132];
    const int t = threadIdx.x;
    const int cb = (blockIdx.x & 7) * 64;
    const int ks = blockIdx.x >> 3;
    const int kb = ks * 128;

    {
        int r = t >> 2, seg = (t & 3) * 32;
#pragma unroll
        for (int i = 0; i < 8; ++i)
            *(float4*)&As[r * 132 + seg + i * 4] =
                *(const float4*)&aggr[(size_t)r * 6144 + kb + seg + i * 4];
    }
    __syncthreads();

    const int r0 = (t >> 4) << 2;
    const int c0 = (t & 15) << 2;
    float acc[4][4];
#pragma unroll
    for (int i = 0; i < 4; ++i)
#pragma unroll
        for (int j = 0; j < 4; ++j) acc[i][j] = 0.f;

#pragma unroll 4
    for (int kk = 0; kk < 128; ++kk) {
        float4 w = *(const float4*)&W[(size_t)(kb + kk) * 512 + cb + c0];
#pragma unroll
        for (int i = 0; i < 4; ++i) {
            float a = As[(r0 + i) * 132 + kk];
            acc[i][0] += a * w.x; acc[i][1] += a * w.y;
            acc[i][2] += a * w.z; acc[i][3] += a * w.w;
        }
    }

    float* pp = part + (size_t)ks * (64 * 512);
#pragma unroll
    for (int i = 0; i < 4; ++i)
        *(float4*)&pp[(size_t)(r0 + i) * 512 + cb + c0] = *(float4*)&acc[i][0];
}

__global__ void k_fc1_reduce(const float* __restrict__ part,
                             const float* __restrict__ bias,
                             const float* __restrict__ g, const float* __restrict__ bb,
                             const float* __restrict__ m, const float* __restrict__ v,
                             float* __restrict__ h1) {
    int i = blockIdx.x * 256 + threadIdx.x;
    if (i >= 64 * 512) return;
    float s = 0.f;
    for (int ks = 0; ks < KSPLIT; ++ks) s += part[ks * 32768 + i];
    int c = i & 511;
    float x = s + bias[c];
    float sl = x / (1.f + __expf(-x));
    h1[i] = (sl - m[c]) * rsqrtf(v[c] + 1e-5f) * g[c] + bb[c];
}

// ---------------- head ----------------

__global__ __launch_bounds__(256)
void k_head(const float* __restrict__ h1,
            const float* __restrict__ fc2w, const float* __restrict__ fc2b,
            const float* __restrict__ g2, const float* __restrict__ b2,
            const float* __restrict__ m2, const float* __restrict__ v2,
            const float* __restrict__ fc3w, const float* __restrict__ fc3b,
            float* __restrict__ out) {
    __shared__ float row[512];
    __shared__ float red[8 * 32];
    __shared__ float h2[32];
    const int b = blockIdx.x, t = threadIdx.x;
    row[t] = h1[(size_t)b * 512 + t];
    row[t + 256] = h1[(size_t)b * 512 + 256 + t];
    __syncthreads();
    {
        int c = t & 31, part = t >> 5;
        float s = 0.f;
        for (int k = part * 64; k < part * 64 + 64; ++k) s += row[k] * fc2w[k * 32 + c];
        red[part * 32 + c] = s;
    }
    __syncthreads();
    if (t < 32) {
        float vv = 0.f;
        for (int p = 0; p < 8; ++p) vv += red[p * 32 + t];
        vv += fc2b[t];
        float sl = vv / (1.f + __expf(-vv));
        h2[t] = (sl - m2[t]) * rsqrtf(v2[t] + 1e-5f) * g2[t] + b2[t];
    }
    __syncthreads();
    if (t == 0) {
        float l0 = fc3b[0], l1 = fc3b[1];
        for (int k = 0; k < 32; ++k) { l0 += h2[k] * fc3w[k * 2]; l1 += h2[k] * fc3w[k * 2 + 1]; }
        float mx = fmaxf(l0, l1);
        float e0 = __expf(l0 - mx), e1 = __expf(l1 - mx);
        float inv = 1.f / (e0 + e1);
        out[b * 2] = e0 * inv;
        out[b * 2 + 1] = e1 * inv;
    }
}

// ---------------- launch ----------------

extern "C" void kernel_launch(void* const* d_in, const int* in_sizes, int n_in,
                              void* d_out, int out_size, void* d_ws, size_t ws_size,
                              hipStream_t stream) {
    (void)in_sizes; (void)n_in; (void)out_size;

    const float* x    = (const float*)d_in[0];
    const int*   ei   = (const int*)d_in[1];
    const float* pe   = (const float*)d_in[2];
    const float* W1   = (const float*)d_in[3];
    const float* b1   = (const float*)d_in[4];
    const float* W2   = (const float*)d_in[5];
    const float* b2   = (const float*)d_in[6];
    const float* fc1w = (const float*)d_in[7];
    const float* fc1b = (const float*)d_in[8];
    const float* fc2w = (const float*)d_in[9];
    const float* fc2b = (const float*)d_in[10];
    const float* fc3w = (const float*)d_in[11];
    const float* fc3b = (const float*)d_in[12];
    const float* bn1g = (const float*)d_in[13];
    const float* bn1b = (const float*)d_in[14];
    const float* bn1m = (const float*)d_in[15];
    const float* bn1v = (const float*)d_in[16];
    const float* bn2g = (const float*)d_in[17];
    const float* bn2b = (const float*)d_in[18];
    const float* bn2m = (const float*)d_in[19];
    const float* bn2v = (const float*)d_in[20];
    float* out = (float*)d_out;

    char* ws = (char*)d_ws;
    unsigned short* t1b  = (unsigned short*)(ws + 0);          // 16,515,072
    unsigned short* qbf  = (unsigned short*)(ws + 16515072);   // 16,515,072
    unsigned short* ctxb = (unsigned short*)(ws + 33030144);   // 16,515,072
    float*          aggr = (float*)(ws + 49545216);            // 1,572,864
    float*          h1   = (float*)(ws + 51118080);            // 131,072
    int*            fill = (int*)  (ws + 51249152);            // 258,048
    int*            csr  = (int*)  (ws + 51507200);            // 16,515,072
    unsigned short* Wt1  = (unsigned short*)(ws + 68022272);   // 24,576
    unsigned short* Wt2  = (unsigned short*)(ws + 68046848);   // 32,768
    float*          part = (float*)qbf;  // fc1 partials (6.3MB) alias qbf (dead after flash)
    if (ws_size < 68079616ull) return;

    hipMemsetAsync(fill, 0, NNODE * sizeof(int), stream);
    k_scatter<<<(NEDGE + 255) / 256, 256, 0, stream>>>(ei, fill, csr);
    k_prepW<<<14, 256, 0, stream>>>(W1, W2, Wt1, Wt2);
    k_gin1<<<NNODE / 128, 256, 0, stream>>>((const float4*)x, fill, csr, Wt1, b1, t1b);
    k_gin2<<<NNODE / 128, 256, 0, stream>>>(t1b, fill, csr, Wt2, b2, pe, qbf);
    k_flash_mfma<<<BATCH * 8, 256, 0, stream>>>(qbf, ctxb);
    k_pool<<<BATCH * WIN, 128, 0, stream>>>(t1b, ctxb, aggr);
    k_fc1_partial<<<8 * KSPLIT, 256, 0, stream>>>(aggr, fc1w, part);
    k_fc1_reduce<<<128, 256, 0, stream>>>(part, fc1b, bn1g, bn1b, bn1m, bn1v, h1);
    k_head<<<BATCH, 256, 0, stream>>>(h1, fc2w, fc2b, bn2g, bn2b, bn2m, bn2v,
                                      fc3w, fc3b, out);
}

// Round 12
// 409.707 us; speedup vs baseline: 1.2674x; 1.2674x over previous
//
#include <hip/hip_runtime.h>
#include <math.h>

#define ROI 84
#define WIN 12
#define HID 128
#define BATCH 64
#define SEQ (ROI * WIN)              // 1008
#define NNODE (BATCH * SEQ)          // 64512
#define NEDGE (NNODE * 16)           // 1032192
#define MAXDEG 64

typedef __attribute__((ext_vector_type(8))) __bf16 bf16x8;
typedef __attribute__((ext_vector_type(4))) float f32x4;
typedef __attribute__((ext_vector_type(8))) unsigned short u16x8;
typedef __attribute__((ext_vector_type(4))) unsigned short u16x4;

__device__ inline unsigned short f2bf(float x) {
    union { float f; unsigned u; } v; v.f = x;
    unsigned r = v.u + 0x7fff + ((v.u >> 16) & 1);   // RNE
    return (unsigned short)(r >> 16);
}

__device__ inline float bf2f(unsigned short u) {
    union { unsigned u; float f; } v; v.u = (unsigned)u << 16;
    return v.f;
}

// ---------------- CSR build ----------------

__global__ void k_scatter(const int* __restrict__ ei, int* __restrict__ fill,
                          int* __restrict__ csr) {
    int e = blockIdx.x * 256 + threadIdx.x;
    if (e >= NEDGE) return;
    bool is64 = true;
#pragma unroll
    for (int k = 0; k < 8; ++k) is64 = is64 && (ei[2 * k + 1] == 0);
    int s, d;
    if (is64) { s = ei[2 * e]; d = ei[2 * (NEDGE + e)]; }
    else      { s = ei[e];     d = ei[NEDGE + e]; }
    if (s < 0 || s >= NNODE || d < 0 || d >= NNODE) return;
    int pos = atomicAdd(&fill[d], 1);
    if (pos < MAXDEG) csr[d * MAXDEG + pos] = s;
}

// ---------------- W -> MFMA B-fragment layout (bf16), both weights ----------------
// Wt[((kb*4+ko)*128+col)*8+j] = W[kb*32+ko*8+j][col]  (0 beyond KACT)

__global__ void k_prepW(const float* __restrict__ W1, const float* __restrict__ W2,
                        unsigned short* __restrict__ Wt1, unsigned short* __restrict__ Wt2) {
    int g = blockIdx.x * 256 + threadIdx.x;
    if (g < 1536) {                                  // Wt1: KB=3, KACT=84
        int col = g & 127, kq = g >> 7;
        u16x8 o;
#pragma unroll
        for (int j = 0; j < 8; ++j) {
            int k = kq * 8 + j;
            o[j] = (k < 84) ? f2bf(W1[(size_t)k * 128 + col]) : (unsigned short)0;
        }
        *(u16x8*)&Wt1[(size_t)g * 8] = o;
    } else if (g < 1536 + 2048) {                    // Wt2: KB=4, KACT=128
        int g2 = g - 1536;
        int col = g2 & 127, kq = g2 >> 7;
        u16x8 o;
#pragma unroll
        for (int j = 0; j < 8; ++j)
            o[j] = f2bf(W2[(size_t)(kq * 8 + j) * 128 + col]);
        *(u16x8*)&Wt2[(size_t)g2 * 8] = o;
    }
}

// ---------------- GIN agg 1: A1b[n][96] = bf16(x[n] + sum_j x[j]) ----------------
// High-TLP gather: one thread per (node, float4-chunk) = NNODE*24 threads.

__global__ void k_agg1b(const float4* __restrict__ x4, const int* __restrict__ fill,
                        const int* __restrict__ csr, unsigned short* __restrict__ A1b) {
    int idx = blockIdx.x * 256 + threadIdx.x;        // NNODE*24
    int n = idx / 24;
    int f4 = idx - n * 24;
    if (f4 >= 21) {                                  // zero pad cols 84..95
        u16x4 z = {0, 0, 0, 0};
        *(u16x4*)&A1b[(size_t)n * 96 + f4 * 4] = z;
        return;
    }
    int deg = fill[n];
    if (deg > MAXDEG) deg = MAXDEG;
    const int* lst = csr + n * MAXDEG;
    float4 s = x4[(size_t)n * 21 + f4];
    int j = 0;
    for (; j + 2 <= deg; j += 2) {
        float4 v0 = x4[(size_t)lst[j] * 21 + f4];
        float4 v1 = x4[(size_t)lst[j + 1] * 21 + f4];
        s.x += v0.x + v1.x; s.y += v0.y + v1.y;
        s.z += v0.z + v1.z; s.w += v0.w + v1.w;
    }
    if (j < deg) {
        float4 v0 = x4[(size_t)lst[j] * 21 + f4];
        s.x += v0.x; s.y += v0.y; s.z += v0.z; s.w += v0.w;
    }
    u16x4 o;
    o[0] = f2bf(s.x); o[1] = f2bf(s.y); o[2] = f2bf(s.z); o[3] = f2bf(s.w);
    *(u16x4*)&A1b[(size_t)n * 96 + f4 * 4] = o;
}

// ---------------- GIN agg 2: A2b[n][128] = bf16(t1b[n] + sum_j t1b[j]) ----------------
// One thread per (node, 8-col chunk) = NNODE*16 threads.

__global__ void k_agg2b(const unsigned short* __restrict__ t1b,
                        const int* __restrict__ fill, const int* __restrict__ csr,
                        unsigned short* __restrict__ A2b) {
    int idx = blockIdx.x * 256 + threadIdx.x;        // NNODE*16
    int n = idx >> 4;
    int f8 = idx & 15;
    int deg = fill[n];
    if (deg > MAXDEG) deg = MAXDEG;
    const int* lst = csr + n * MAXDEG;
    u16x8 sv = *(const u16x8*)&t1b[(size_t)n * 128 + f8 * 8];
    float s[8];
#pragma unroll
    for (int e = 0; e < 8; ++e) s[e] = bf2f(sv[e]);
    int j = 0;
    for (; j + 2 <= deg; j += 2) {
        u16x8 v0 = *(const u16x8*)&t1b[(size_t)lst[j] * 128 + f8 * 8];
        u16x8 v1 = *(const u16x8*)&t1b[(size_t)lst[j + 1] * 128 + f8 * 8];
#pragma unroll
        for (int e = 0; e < 8; ++e) s[e] += bf2f(v0[e]) + bf2f(v1[e]);
    }
    if (j < deg) {
        u16x8 v0 = *(const u16x8*)&t1b[(size_t)lst[j] * 128 + f8 * 8];
#pragma unroll
        for (int e = 0; e < 8; ++e) s[e] += bf2f(v0[e]);
    }
    u16x8 o;
#pragma unroll
    for (int e = 0; e < 8; ++e) o[e] = f2bf(s[e]);
    *(u16x8*)&A2b[(size_t)n * 128 + f8 * 8] = o;
}

// ---------------- MFMA GEMM: out[N,128] = A[N,KB*32]bf16 @ Wt + bias (+pe) ----------
// 504 blocks x 128 rows, 4 waves; wave w: rows w*32..w*32+32 (2 frags) x 128 cols.

template <int KB, bool ADD_PE>
__global__ __launch_bounds__(256)
void k_gemm_mfma(const unsigned short* __restrict__ A,
                 const unsigned short* __restrict__ Wt,
                 const float* __restrict__ bias, const float* __restrict__ pe,
                 unsigned short* __restrict__ ob) {
    __shared__ unsigned short As[128 * KB * 32];
    const int t = threadIdx.x;
    const int lane = t & 63;
    const int w = t >> 6;
    const int r = lane & 15;
    const int h = lane >> 4;
    const int row0 = blockIdx.x * 128;

    // stage A tile (128 x KB*32 bf16), 16B units, swizzled
    for (int u = t; u < 128 * KB * 4; u += 256) {
        int row = u / (KB * 4), seg = u - row * (KB * 4);
        u16x8 v = *(const u16x8*)&A[(size_t)(row0 + row) * (KB * 32) + seg * 8];
        *(u16x8*)((char*)As + ((row * (KB * 64) + seg * 16) ^ ((row & 7) << 4))) = v;
    }
    __syncthreads();

    f32x4 acc0[8], acc1[8];
#pragma unroll
    for (int cb = 0; cb < 8; ++cb) {
        acc0[cb] = (f32x4){0.f, 0.f, 0.f, 0.f};
        acc1[cb] = (f32x4){0.f, 0.f, 0.f, 0.f};
    }

#pragma unroll
    for (int kb = 0; kb < KB; ++kb) {
        const int ra = w * 32 + r;
        const int rb = w * 32 + 16 + r;
        bf16x8 pa0 = *(const bf16x8*)((const char*)As +
            ((ra * (KB * 64) + kb * 64 + h * 16) ^ ((ra & 7) << 4)));
        bf16x8 pa1 = *(const bf16x8*)((const char*)As +
            ((rb * (KB * 64) + kb * 64 + h * 16) ^ ((rb & 7) << 4)));
#pragma unroll
        for (int cb = 0; cb < 8; ++cb) {
            bf16x8 wv = *(const bf16x8*)&Wt[(size_t)((kb * 4 + h) * 128 + cb * 16 + r) * 8];
            acc0[cb] = __builtin_amdgcn_mfma_f32_16x16x32_bf16(pa0, wv, acc0[cb], 0, 0, 0);
            acc1[cb] = __builtin_amdgcn_mfma_f32_16x16x32_bf16(pa1, wv, acc1[cb], 0, 0, 0);
        }
    }

    // epilogue (C/D: col = lane&15 = r, row = h*4+i)
#pragma unroll
    for (int cb = 0; cb < 8; ++cb) {
        int col = cb * 16 + r;
        float bv = bias[col];
#pragma unroll
        for (int i = 0; i < 4; ++i) {
            int g0 = row0 + w * 32 + h * 4 + i;
            int g1 = g0 + 16;
            float v0 = acc0[cb][i] + bv;
            float v1 = acc1[cb][i] + bv;
            if (ADD_PE) {
                v0 += pe[(size_t)(g0 % SEQ) * 128 + col];
                v1 += pe[(size_t)(g1 % SEQ) * 128 + col];
            }
            ob[(size_t)g0 * 128 + col] = f2bf(v0);
            ob[(size_t)g1 * 128 + col] = f2bf(v1);
        }
    }
}

// ---------------- MFMA flash self-attention (q = k = v) ----------------
// 512 blocks (64 batches x 8 q-tiles of 128 rows), 4 waves; XCD swizzle keeps
// each batch's K/V L2-resident. Register-prefetched staging; defer-rescale THR=8.

struct Stg { u16x8 a0, a1, c0, c1; };

__device__ inline Stg load_stage(const unsigned short* qb, int kt, int t) {
    const int kp = t >> 3;
    const int dseg = (t & 7) * 16;
    const int g0 = kt * 64 + kp * 2;
    const u16x8 zz = {0, 0, 0, 0, 0, 0, 0, 0};
    Stg s; s.a0 = zz; s.a1 = zz; s.c0 = zz; s.c1 = zz;
    if (g0 < SEQ) {
        s.a0 = *(const u16x8*)&qb[(size_t)g0 * 128 + dseg];
        s.a1 = *(const u16x8*)&qb[(size_t)g0 * 128 + dseg + 8];
    }
    if (g0 + 1 < SEQ) {
        s.c0 = *(const u16x8*)&qb[(size_t)(g0 + 1) * 128 + dseg];
        s.c1 = *(const u16x8*)&qb[(size_t)(g0 + 1) * 128 + dseg + 8];
    }
    return s;
}

__device__ inline void write_stage(unsigned short* Ks, unsigned short* Vt,
                                   const Stg& s, int t) {
    const int kp = t >> 3;
    const int dseg = (t & 7) * 16;
    const int k0 = kp * 2, k1 = k0 + 1;
    *(u16x8*)((char*)Ks + ((k0 * 256 + dseg * 2) ^ ((k0 & 7) << 4))) = s.a0;
    *(u16x8*)((char*)Ks + ((k0 * 256 + dseg * 2 + 16) ^ ((k0 & 7) << 4))) = s.a1;
    *(u16x8*)((char*)Ks + ((k1 * 256 + dseg * 2) ^ ((k1 & 7) << 4))) = s.c0;
    *(u16x8*)((char*)Ks + ((k1 * 256 + dseg * 2 + 16) ^ ((k1 & 7) << 4))) = s.c1;
#pragma unroll
    for (int j = 0; j < 16; ++j) {
        int d = dseg + j;
        unsigned short lo = (j < 8) ? s.a0[j] : s.a1[j - 8];
        unsigned short hi = (j < 8) ? s.c0[j] : s.c1[j - 8];
        unsigned val = (unsigned)lo | ((unsigned)hi << 16);
        *(unsigned*)((char*)Vt + ((d * 128 + k0 * 2) ^ ((d & 7) << 4)
                                  ^ (((d >> 4) & 3) << 5))) = val;
    }
}

__global__ __launch_bounds__(256, 2)
void k_flash_mfma(const unsigned short* __restrict__ qbf,
                  unsigned short* __restrict__ ctxb) {
    __shared__ unsigned short Ks[64 * 128];
    __shared__ unsigned short Vt[128 * 64];
    __shared__ unsigned short Pl[4][2][1024];

    const int t = threadIdx.x;
    const int lane = t & 63;
    const int w = t >> 6;
    const int r = lane & 15;
    const int h = lane >> 4;
    const int p = blockIdx.x;
    const int grp = p >> 3;
    const int b = (grp >> 3) * 8 + (p & 7);
    const int qrow0 = (grp & 7) * 128;
    const unsigned short* qb = qbf + (size_t)b * SEQ * HID;

    bf16x8 Qf[2][4];
#pragma unroll
    for (int qa = 0; qa < 2; ++qa) {
        int qrow = qrow0 + w * 32 + qa * 16 + r;
        int qrc = qrow < SEQ ? qrow : SEQ - 1;
#pragma unroll
        for (int ds = 0; ds < 4; ++ds)
            Qf[qa][ds] = *(const bf16x8*)&qb[(size_t)qrc * 128 + ds * 32 + h * 8];
    }

    f32x4 O[2][8];
#pragma unroll
    for (int qa = 0; qa < 2; ++qa)
#pragma unroll
        for (int dt = 0; dt < 8; ++dt) O[qa][dt] = (f32x4){0.f, 0.f, 0.f, 0.f};
    float m_[2][4], l_[2][4];
#pragma unroll
    for (int qa = 0; qa < 2; ++qa)
#pragma unroll
        for (int i = 0; i < 4; ++i) { m_[qa][i] = -1e30f; l_[qa][i] = 0.f; }

    const float scale = 0.08838834764831845f;  // 1/sqrt(128)

    Stg cur = load_stage(qb, 0, t);

    for (int kt = 0; kt < 16; ++kt) {
        __syncthreads();
        write_stage(Ks, Vt, cur, t);
        if (kt < 15) cur = load_stage(qb, kt + 1, t);
        __syncthreads();

        // ---- QK^T ----
        f32x4 S[2][4];
        __builtin_amdgcn_s_setprio(1);
#pragma unroll
        for (int kt4 = 0; kt4 < 4; ++kt4) {
            int key = kt4 * 16 + r;
            f32x4 s0 = (f32x4){0.f, 0.f, 0.f, 0.f};
            f32x4 s1 = (f32x4){0.f, 0.f, 0.f, 0.f};
#pragma unroll
            for (int ds = 0; ds < 4; ++ds) {
                bf16x8 kb = *(const bf16x8*)((const char*)Ks +
                    ((key * 256 + (ds * 32 + h * 8) * 2) ^ ((key & 7) << 4)));
                s0 = __builtin_amdgcn_mfma_f32_16x16x32_bf16(Qf[0][ds], kb, s0, 0, 0, 0);
                s1 = __builtin_amdgcn_mfma_f32_16x16x32_bf16(Qf[1][ds], kb, s1, 0, 0, 0);
            }
            S[0][kt4] = s0; S[1][kt4] = s1;
        }
        __builtin_amdgcn_s_setprio(0);

        // ---- scale + mask + per-row tile max ----
        float pmax[2][4];
#pragma unroll
        for (int qa = 0; qa < 2; ++qa)
#pragma unroll
            for (int i = 0; i < 4; ++i) pmax[qa][i] = -1e30f;
#pragma unroll
        for (int qa = 0; qa < 2; ++qa)
#pragma unroll
            for (int kt4 = 0; kt4 < 4; ++kt4) {
                bool kvalid = (kt * 64 + kt4 * 16 + r) < SEQ;
#pragma unroll
                for (int i = 0; i < 4; ++i) {
                    float v = kvalid ? S[qa][kt4][i] * scale : -1e30f;
                    S[qa][kt4][i] = v;
                    pmax[qa][i] = fmaxf(pmax[qa][i], v);
                }
            }
#pragma unroll
        for (int qa = 0; qa < 2; ++qa)
#pragma unroll
            for (int i = 0; i < 4; ++i) {
                float v = pmax[qa][i];
                v = fmaxf(v, __shfl_xor(v, 1));
                v = fmaxf(v, __shfl_xor(v, 2));
                v = fmaxf(v, __shfl_xor(v, 4));
                v = fmaxf(v, __shfl_xor(v, 8));
                pmax[qa][i] = v;
            }

        // ---- defer-rescale: only update m/rescale when growth > THR ----
        float need = -1e30f;
#pragma unroll
        for (int qa = 0; qa < 2; ++qa)
#pragma unroll
            for (int i = 0; i < 4; ++i)
                need = fmaxf(need, pmax[qa][i] - m_[qa][i]);
        need = fmaxf(need, __shfl_xor(need, 16));
        need = fmaxf(need, __shfl_xor(need, 32));
        if (need > 8.f) {
#pragma unroll
            for (int qa = 0; qa < 2; ++qa)
#pragma unroll
                for (int i = 0; i < 4; ++i) {
                    float mn = fmaxf(m_[qa][i], pmax[qa][i]);
                    float alpha = __expf(m_[qa][i] - mn);
                    m_[qa][i] = mn;
                    l_[qa][i] *= alpha;
#pragma unroll
                    for (int dt = 0; dt < 8; ++dt) O[qa][dt][i] *= alpha;
                }
        }

        // ---- P = exp(S - m), accumulate l, store P to LDS ----
#pragma unroll
        for (int qa = 0; qa < 2; ++qa) {
            char* Pw = (char*)&Pl[w][qa][0];
            float ps[4] = {0.f, 0.f, 0.f, 0.f};
#pragma unroll
            for (int kt4 = 0; kt4 < 4; ++kt4)
#pragma unroll
                for (int i = 0; i < 4; ++i) {
                    float pv = __expf(S[qa][kt4][i] - m_[qa][i]);
                    ps[i] += pv;
                    *(unsigned short*)(Pw + (((h * 4 + i) * 128 + (kt4 * 16 + r) * 2)
                                             ^ (((h * 4 + i) & 7) << 4))) = f2bf(pv);
                }
#pragma unroll
            for (int i = 0; i < 4; ++i) {
                float v = ps[i];
                v += __shfl_xor(v, 1);
                v += __shfl_xor(v, 2);
                v += __shfl_xor(v, 4);
                v += __shfl_xor(v, 8);
                l_[qa][i] += v;
            }
        }

        // ---- PV ----
        __builtin_amdgcn_s_setprio(1);
#pragma unroll
        for (int kstep = 0; kstep < 2; ++kstep) {
            bf16x8 pa0 = *(const bf16x8*)((const char*)&Pl[w][0][0] +
                ((r * 128 + (kstep * 32 + h * 8) * 2) ^ ((r & 7) << 4)));
            bf16x8 pa1 = *(const bf16x8*)((const char*)&Pl[w][1][0] +
                ((r * 128 + (kstep * 32 + h * 8) * 2) ^ ((r & 7) << 4)));
#pragma unroll
            for (int dt = 0; dt < 8; ++dt) {
                int d = dt * 16 + r;
                bf16x8 vb = *(const bf16x8*)((const char*)Vt +
                    ((d * 128 + (kstep * 32 + h * 8) * 2) ^ ((d & 7) << 4)
                     ^ (((d >> 4) & 3) << 5)));
                O[0][dt] = __builtin_amdgcn_mfma_f32_16x16x32_bf16(pa0, vb, O[0][dt], 0, 0, 0);
                O[1][dt] = __builtin_amdgcn_mfma_f32_16x16x32_bf16(pa1, vb, O[1][dt], 0, 0, 0);
            }
        }
        __builtin_amdgcn_s_setprio(0);
    }

    // ---- epilogue: bf16 ctx ----
#pragma unroll
    for (int qa = 0; qa < 2; ++qa)
#pragma unroll
        for (int i = 0; i < 4; ++i) {
            int qq = qrow0 + w * 32 + qa * 16 + h * 4 + i;
            if (qq < SEQ) {
                float inv = 1.f / l_[qa][i];
                size_t base = ((size_t)b * SEQ + qq) * 128 + r;
#pragma unroll
                for (int dt = 0; dt < 8; ++dt)
                    ctxb[base + dt * 16] = f2bf(O[qa][dt][i] * inv);
            }
        }
}

// ---------------- pooling (bf16 inputs) ----------------

__global__ void k_pool(const unsigned short* __restrict__ t1b,
                       const unsigned short* __restrict__ ctxb,
                       float* __restrict__ aggr) {
    int bw = blockIdx.x;
    int b = bw / WIN, w = bw - b * WIN;
    int c = threadIdx.x;
    const unsigned short* p1 = t1b + ((size_t)(b * SEQ + w * ROI)) * HID + c;
    const unsigned short* p2 = ctxb + ((size_t)(b * SEQ + w * ROI)) * HID + c;
    float mx1 = -INFINITY, sm1 = 0.f, mx2 = -INFINITY, sm2 = 0.f;
    for (int r = 0; r < ROI; ++r) {
        float a = bf2f(p1[r * HID]); mx1 = fmaxf(mx1, a); sm1 += a;
        float d = bf2f(p2[r * HID]); mx2 = fmaxf(mx2, d); sm2 += d;
    }
    float* o = aggr + (size_t)b * 6144 + w * 512;
    o[c] = mx1;
    o[128 + c] = sm1 * (1.f / 84.f);
    o[256 + c] = mx2;
    o[384 + c] = sm2 * (1.f / 84.f);
}

// ---------------- fc1 split-K ----------------

#define KSPLIT 48

__global__ __launch_bounds__(256)
void k_fc1_partial(const float* __restrict__ aggr, const float* __restrict__ W,
                   float* __restrict__ part) {
    __shared__ float As[64 * 132];
    const int t = threadIdx.x;
    const int cb = (blockIdx.x & 7) * 64;
    const int ks = blockIdx.x >> 3;
    const int kb = ks * 128;

    {
        int r = t >> 2, seg = (t & 3) * 32;
#pragma unroll
        for (int i = 0; i < 8; ++i)
            *(float4*)&As[r * 132 + seg + i * 4] =
                *(const float4*)&aggr[(size_t)r * 6144 + kb + seg + i * 4];
    }
    __syncthreads();

    const int r0 = (t >> 4) << 2;
    const int c0 = (t & 15) << 2;
    float acc[4][4];
#pragma unroll
    for (int i = 0; i < 4; ++i)
#pragma unroll
        for (int j = 0; j < 4; ++j) acc[i][j] = 0.f;

#pragma unroll 4
    for (int kk = 0; kk < 128; ++kk) {
        float4 w = *(const float4*)&W[(size_t)(kb + kk) * 512 + cb + c0];
#pragma unroll
        for (int i = 0; i < 4; ++i) {
            float a = As[(r0 + i) * 132 + kk];
            acc[i][0] += a * w.x; acc[i][1] += a * w.y;
            acc[i][2] += a * w.z; acc[i][3] += a * w.w;
        }
    }

    float* pp = part + (size_t)ks * (64 * 512);
#pragma unroll
    for (int i = 0; i < 4; ++i)
        *(float4*)&pp[(size_t)(r0 + i) * 512 + cb + c0] = *(float4*)&acc[i][0];
}

__global__ void k_fc1_reduce(const float* __restrict__ part,
                             const float* __restrict__ bias,
                             const float* __restrict__ g, const float* __restrict__ bb,
                             const float* __restrict__ m, const float* __restrict__ v,
                             float* __restrict__ h1) {
    int i = blockIdx.x * 256 + threadIdx.x;
    if (i >= 64 * 512) return;
    float s = 0.f;
    for (int ks = 0; ks < KSPLIT; ++ks) s += part[ks * 32768 + i];
    int c = i & 511;
    float x = s + bias[c];
    float sl = x / (1.f + __expf(-x));
    h1[i] = (sl - m[c]) * rsqrtf(v[c] + 1e-5f) * g[c] + bb[c];
}

// ---------------- head ----------------

__global__ __launch_bounds__(256)
void k_head(const float* __restrict__ h1,
            const float* __restrict__ fc2w, const float* __restrict__ fc2b,
            const float* __restrict__ g2, const float* __restrict__ b2,
            const float* __restrict__ m2, const float* __restrict__ v2,
            const float* __restrict__ fc3w, const float* __restrict__ fc3b,
            float* __restrict__ out) {
    __shared__ float row[512];
    __shared__ float red[8 * 32];
    __shared__ float h2[32];
    const int b = blockIdx.x, t = threadIdx.x;
    row[t] = h1[(size_t)b * 512 + t];
    row[t + 256] = h1[(size_t)b * 512 + 256 + t];
    __syncthreads();
    {
        int c = t & 31, part = t >> 5;
        float s = 0.f;
        for (int k = part * 64; k < part * 64 + 64; ++k) s += row[k] * fc2w[k * 32 + c];
        red[part * 32 + c] = s;
    }
    __syncthreads();
    if (t < 32) {
        float vv = 0.f;
        for (int p = 0; p < 8; ++p) vv += red[p * 32 + t];
        vv += fc2b[t];
        float sl = vv / (1.f + __expf(-vv));
        h2[t] = (sl - m2[t]) * rsqrtf(v2[t] + 1e-5f) * g2[t] + b2[t];
    }
    __syncthreads();
    if (t == 0) {
        float l0 = fc3b[0], l1 = fc3b[1];
        for (int k = 0; k < 32; ++k) { l0 += h2[k] * fc3w[k * 2]; l1 += h2[k] * fc3w[k * 2 + 1]; }
        float mx = fmaxf(l0, l1);
        float e0 = __expf(l0 - mx), e1 = __expf(l1 - mx);
        float inv = 1.f / (e0 + e1);
        out[b * 2] = e0 * inv;
        out[b * 2 + 1] = e1 * inv;
    }
}

// ---------------- launch ----------------

extern "C" void kernel_launch(void* const* d_in, const int* in_sizes, int n_in,
                              void* d_out, int out_size, void* d_ws, size_t ws_size,
                              hipStream_t stream) {
    (void)in_sizes; (void)n_in; (void)out_size;

    const float* x    = (const float*)d_in[0];
    const int*   ei   = (const int*)d_in[1];
    const float* pe   = (const float*)d_in[2];
    const float* W1   = (const float*)d_in[3];
    const float* b1   = (const float*)d_in[4];
    const float* W2   = (const float*)d_in[5];
    const float* b2   = (const float*)d_in[6];
    const float* fc1w = (const float*)d_in[7];
    const float* fc1b = (const float*)d_in[8];
    const float* fc2w = (const float*)d_in[9];
    const float* fc2b = (const float*)d_in[10];
    const float* fc3w = (const float*)d_in[11];
    const float* fc3b = (const float*)d_in[12];
    const float* bn1g = (const float*)d_in[13];
    const float* bn1b = (const float*)d_in[14];
    const float* bn1m = (const float*)d_in[15];
    const float* bn1v = (const float*)d_in[16];
    const float* bn2g = (const float*)d_in[17];
    const float* bn2b = (const float*)d_in[18];
    const float* bn2m = (const float*)d_in[19];
    const float* bn2v = (const float*)d_in[20];
    float* out = (float*)d_out;

    char* ws = (char*)d_ws;
    unsigned short* A1b  = (unsigned short*)(ws + 0);          // N*96*2  = 12,386,304
    unsigned short* A2b  = (unsigned short*)(ws + 12386304);   // N*128*2 = 16,515,072
    unsigned short* t1b  = (unsigned short*)(ws + 28901376);   // 16,515,072
    unsigned short* qbf  = (unsigned short*)(ws + 45416448);   // 16,515,072
    unsigned short* ctxb = (unsigned short*)(ws + 61931520);   // 16,515,072
    float*          aggr = (float*)(ws + 78446592);            // 1,572,864
    float*          h1   = (float*)(ws + 80019456);            // 131,072
    int*            fill = (int*)  (ws + 80150528);            // 258,048
    int*            csr  = (int*)  (ws + 80408576);            // 16,515,072
    unsigned short* Wt1  = (unsigned short*)(ws + 96923648);   // 24,576
    unsigned short* Wt2  = (unsigned short*)(ws + 96948224);   // 32,768
    float*          part = (float*)A1b;  // fc1 partials (6.3MB) alias A1b (dead by then)
    if (ws_size < 96980992ull) return;

    hipMemsetAsync(fill, 0, NNODE * sizeof(int), stream);
    k_scatter<<<(NEDGE + 255) / 256, 256, 0, stream>>>(ei, fill, csr);
    k_prepW<<<14, 256, 0, stream>>>(W1, W2, Wt1, Wt2);
    k_agg1b<<<(NNODE * 24) / 256, 256, 0, stream>>>((const float4*)x, fill, csr, A1b);
    k_gemm_mfma<3, false><<<NNODE / 128, 256, 0, stream>>>(A1b, Wt1, b1, nullptr, t1b);
    k_agg2b<<<(NNODE * 16) / 256, 256, 0, stream>>>(t1b, fill, csr, A2b);
    k_gemm_mfma<4, true><<<NNODE / 128, 256, 0, stream>>>(A2b, Wt2, b2, pe, qbf);
    k_flash_mfma<<<BATCH * 8, 256, 0, stream>>>(qbf, ctxb);
    k_pool<<<BATCH * WIN, 128, 0, stream>>>(t1b, ctxb, aggr);
    k_fc1_partial<<<8 * KSPLIT, 256, 0, stream>>>(aggr, fc1w, part);
    k_fc1_reduce<<<128, 256, 0, stream>>>(part, fc1b, bn1g, bn1b, bn1m, bn1v, h1);
    k_head<<<BATCH, 256, 0, stream>>>(h1, fc2w, fc2b, bn2g, bn2b, bn2m, bn2v,
                                      fc3w, fc3b, out);
}